// Round 1
// baseline (1150.509 us; speedup 1.0000x reference)
//
#include <hip/hip_runtime.h>

#define NELEM 10
#define C 128

__device__ inline unsigned short f2bf(float f) {
    unsigned x = __float_as_uint(f);
    unsigned r = (x + 0x7fffu + ((x >> 16) & 1u)) >> 16;
    return (unsigned short)r;
}
__device__ inline float bf2f(unsigned short b) {
    return __uint_as_float(((unsigned)b) << 16);
}

// ---------------- small prep kernels ----------------

__global__ void k_tables(const float* __restrict__ W_embed, const float* __restrict__ W_up,
                         const float* __restrict__ W_skip,
                         float* __restrict__ h_elem, float* __restrict__ sc0e) {
    int t = threadIdx.x;
    for (int idx = t; idx < NELEM * C; idx += 256) {
        int a = idx >> 7, c = idx & 127;
        float acc = 0.f, acc2 = 0.f;
        for (int k = 0; k < C; ++k) {
            float we = W_embed[a * C + k];
            acc  = fmaf(we, W_up[k * C + c], acc);
            acc2 = fmaf(we, W_skip[(k * NELEM + a) * C + c], acc2);
        }
        h_elem[idx] = acc;
        sc0e[idx] = acc2;
    }
}

__global__ void k_elem(const float* __restrict__ x, int* __restrict__ elem, int n) {
    int i = blockIdx.x * 256 + threadIdx.x;
    if (i >= n) return;
    int a = 0;
    float best = x[i * NELEM];
    for (int j = 1; j < NELEM; ++j) {
        float v = x[i * NELEM + j];
        if (v > best) { best = v; a = j; }
    }
    elem[i] = a;
}

__global__ void k_transpose(const float* __restrict__ Wr2, const float* __restrict__ Wr3,
                            const float* __restrict__ Wr4,
                            float* __restrict__ W2T, float* __restrict__ W3T,
                            float* __restrict__ W4T) {
    int i = blockIdx.x * 256 + threadIdx.x;
    if (i < 4096) { int j = i >> 6, k = i & 63; W2T[i] = Wr2[k * 64 + j]; }
    int i2 = i - 4096;
    if (i2 >= 0 && i2 < 4096) { int j = i2 >> 6, k = i2 & 63; W3T[i2] = Wr3[k * 64 + j]; }
    int i3 = i - 8192;
    if (i3 >= 0 && i3 < 32768) { int j = i3 >> 6, k = i3 & 63; W4T[i3] = Wr4[k * 512 + j]; }
}

// ---------------- CSR build ----------------

__global__ void k_hist(const int* __restrict__ ei, int* __restrict__ deg, int E) {
    int e = blockIdx.x * 256 + threadIdx.x;
    if (e < E) atomicAdd(&deg[ei[E + e]], 1);
}

__global__ void k_scan(const int* __restrict__ deg, int* __restrict__ offs, int n) {
    __shared__ int sums[1024];
    int tid = threadIdx.x;
    int base = tid * 8;
    int loc[8];
    int s = 0;
#pragma unroll
    for (int i = 0; i < 8; ++i) {
        loc[i] = s;
        if (base + i < n) s += deg[base + i];
    }
    sums[tid] = s;
    __syncthreads();
    for (int st = 1; st < 1024; st <<= 1) {
        int v = 0;
        if (tid >= st) v = sums[tid - st];
        __syncthreads();
        sums[tid] += v;
        __syncthreads();
    }
    int excl = sums[tid] - s;
#pragma unroll
    for (int i = 0; i < 8; ++i)
        if (base + i < n) offs[base + i] = excl + loc[i];
    if (tid == 1023) offs[n] = sums[1023];
}

__global__ void k_scatter(const int* __restrict__ ei, const int* __restrict__ offs,
                          int* __restrict__ cur, int* __restrict__ csr, int E) {
    int e = blockIdx.x * 256 + threadIdx.x;
    if (e < E) {
        int r = ei[E + e];
        int p = atomicAdd(&cur[r], 1);
        csr[offs[r] + p] = e;
    }
}

// ---------------- edge kernel: Y + radial MLP ----------------

__global__ __launch_bounds__(256) void k_edge(
    const float* __restrict__ evec, const float* __restrict__ elen,
    const float* __restrict__ Wr1,
    const float* __restrict__ W2T, const float* __restrict__ W3T,
    const float* __restrict__ W4T,
    float* __restrict__ Yw, unsigned short* __restrict__ Rw, int E)
{
    __shared__ float t_lds[256 * 65];
    const int tid = threadIdx.x;
    const int e = blockIdx.x * 256 + tid;
    if (e >= E) return;

    float vx = evec[3 * e], vy = evec[3 * e + 1], vz = evec[3 * e + 2];
    float inv = rsqrtf(vx * vx + vy * vy + vz * vz);
    float ux = vx * inv, uy = vy * inv, uz = vz * inv;

    const float s3    = 1.7320508075688772f;
    const float s5h   = 1.118033988749895f;   // 0.5*sqrt(5)
    const float s15   = 3.872983346207417f;
    const float s15h  = 1.9364916731037085f;  // 0.5*sqrt(15)
    const float s70_4 = 2.091650066335189f;   // sqrt(70)/4
    const float s105  = 10.246950765959598f;
    const float s105_2= 5.123475382979799f;
    const float s42_4 = 1.6201851746019651f;  // sqrt(42)/4
    const float s7_2  = 1.3228756555322954f;  // sqrt(7)/2

    float xx = ux * ux, yy = uy * uy, zz = uz * uz;
    float4* yo = reinterpret_cast<float4*>(Yw + ((size_t)e << 4));
    yo[0] = make_float4(1.0f, s3 * ux, s3 * uy, s3 * uz);
    yo[1] = make_float4(s15 * ux * uy, s15 * uy * uz, s5h * (3.0f * zz - 1.0f), s15 * ux * uz);
    yo[2] = make_float4(s15h * (xx - yy),
                        s70_4 * uy * (3.0f * xx - yy),
                        s105 * ux * uy * uz,
                        s42_4 * uy * (5.0f * zz - 1.0f));
    yo[3] = make_float4(s7_2 * uz * (5.0f * zz - 3.0f),
                        s42_4 * ux * (5.0f * zz - 1.0f),
                        s105_2 * uz * (xx - yy),
                        s70_4 * ux * (xx - 3.0f * yy));

    // radial basis: sqrt(2/5)*sin(n*pi*u)/r * env(u), u = r/5
    float r = elen[e];
    float u = r * 0.2f;
    float u2 = u * u;
    float u5 = u2 * u2 * u;
    float env = 1.0f - 21.0f * u5 + 35.0f * u5 * u - 15.0f * u5 * u2;
    if (u >= 1.0f) env = 0.0f;
    float th = 3.14159265358979323846f * u;
    float s1 = __sinf(th), c1 = __cosf(th);
    float pref = 0.6324555320336759f * env / r;
    float ef[8];
    float sn = s1, cn = c1;
    ef[0] = pref * sn;
#pragma unroll
    for (int nn = 1; nn < 8; ++nn) {
        float sn1 = sn * c1 + cn * s1;
        float cn1 = cn * c1 - sn * s1;
        sn = sn1; cn = cn1;
        ef[nn] = pref * sn;
    }

    // layer 1: 8 -> 64 + silu (weights row-major, uniform loads)
    float t[64];
#pragma unroll
    for (int j = 0; j < 64; ++j) t[j] = 0.0f;
#pragma unroll
    for (int i = 0; i < 8; ++i) {
        const float4* w1r = reinterpret_cast<const float4*>(Wr1 + i * 64);
        float efi = ef[i];
#pragma unroll
        for (int j4 = 0; j4 < 16; ++j4) {
            float4 w = w1r[j4];
            t[4 * j4 + 0] = fmaf(efi, w.x, t[4 * j4 + 0]);
            t[4 * j4 + 1] = fmaf(efi, w.y, t[4 * j4 + 1]);
            t[4 * j4 + 2] = fmaf(efi, w.z, t[4 * j4 + 2]);
            t[4 * j4 + 3] = fmaf(efi, w.w, t[4 * j4 + 3]);
        }
    }
#pragma unroll
    for (int j = 0; j < 64; ++j) {
        float v = t[j];
        t[j] = v * __builtin_amdgcn_rcpf(1.0f + __expf(-v));
    }

    float* myt = t_lds + tid * 65;

    // layer 2: 64 -> 64 + silu
#pragma unroll 1
    for (int j = 0; j < 64; ++j) {
        const float4* wr = reinterpret_cast<const float4*>(W2T + (j << 6));
        float a0 = 0.f, a1 = 0.f, a2 = 0.f, a3 = 0.f;
#pragma unroll
        for (int i4 = 0; i4 < 16; ++i4) {
            float4 w = wr[i4];
            a0 = fmaf(t[4 * i4 + 0], w.x, a0);
            a1 = fmaf(t[4 * i4 + 1], w.y, a1);
            a2 = fmaf(t[4 * i4 + 2], w.z, a2);
            a3 = fmaf(t[4 * i4 + 3], w.w, a3);
        }
        float sum = (a0 + a1) + (a2 + a3);
        myt[j] = sum * __builtin_amdgcn_rcpf(1.0f + __expf(-sum));
    }
#pragma unroll
    for (int j = 0; j < 64; ++j) t[j] = myt[j];

    // layer 3: 64 -> 64 + silu
#pragma unroll 1
    for (int j = 0; j < 64; ++j) {
        const float4* wr = reinterpret_cast<const float4*>(W3T + (j << 6));
        float a0 = 0.f, a1 = 0.f, a2 = 0.f, a3 = 0.f;
#pragma unroll
        for (int i4 = 0; i4 < 16; ++i4) {
            float4 w = wr[i4];
            a0 = fmaf(t[4 * i4 + 0], w.x, a0);
            a1 = fmaf(t[4 * i4 + 1], w.y, a1);
            a2 = fmaf(t[4 * i4 + 2], w.z, a2);
            a3 = fmaf(t[4 * i4 + 3], w.w, a3);
        }
        float sum = (a0 + a1) + (a2 + a3);
        myt[j] = sum * __builtin_amdgcn_rcpf(1.0f + __expf(-sum));
    }
#pragma unroll
    for (int j = 0; j < 64; ++j) t[j] = myt[j];

    // layer 4: 64 -> 512 (no act), store bf16 pairs
    unsigned* op = reinterpret_cast<unsigned*>(Rw + ((size_t)e << 9));
#pragma unroll 1
    for (int j2 = 0; j2 < 256; ++j2) {
        const float4* wr0 = reinterpret_cast<const float4*>(W4T + ((size_t)(2 * j2) << 6));
        const float4* wr1 = wr0 + 16;
        float a0 = 0.f, a1 = 0.f, a2 = 0.f, a3 = 0.f;
        float b0 = 0.f, b1 = 0.f, b2 = 0.f, b3 = 0.f;
#pragma unroll
        for (int i4 = 0; i4 < 16; ++i4) {
            float4 wA = wr0[i4], wB = wr1[i4];
            a0 = fmaf(t[4 * i4 + 0], wA.x, a0); b0 = fmaf(t[4 * i4 + 0], wB.x, b0);
            a1 = fmaf(t[4 * i4 + 1], wA.y, a1); b1 = fmaf(t[4 * i4 + 1], wB.y, b1);
            a2 = fmaf(t[4 * i4 + 2], wA.z, a2); b2 = fmaf(t[4 * i4 + 2], wB.z, b2);
            a3 = fmaf(t[4 * i4 + 3], wA.w, a3); b3 = fmaf(t[4 * i4 + 3], wB.w, b3);
        }
        float sA = (a0 + a1) + (a2 + a3);
        float sB = (b0 + b1) + (b2 + b3);
        op[j2] = (unsigned)f2bf(sA) | ((unsigned)f2bf(sB) << 16);
    }
}

// ---------------- fused node kernel ----------------
// block = 256 threads, 4 nodes/block. thread: c/d = tid&127, mg = tid>>7.

__global__ __launch_bounds__(256) void k_node(
    const int* __restrict__ ei, const int* __restrict__ offs, const int* __restrict__ csr,
    const int* __restrict__ elem,
    const float* __restrict__ Yw, const unsigned short* __restrict__ Rw,
    const float* __restrict__ h_elem, const float* __restrict__ sc0e,
    const float* __restrict__ W_out, const float* __restrict__ Wp0,
    const float* __restrict__ Wp1, const float* __restrict__ Wlin0,
    const float* __restrict__ Wlin1, float* __restrict__ out, int E)
{
    __shared__ float aggT[128][68];      // [c][ni*16+m] (padded)
    __shared__ float A_lds[4][16][128];
    __shared__ float p_lds[4][4][128];
    __shared__ int s_e[64];
    __shared__ int s_a[64];

    const int tid = threadIdx.x;
    const int c = tid & 127;
    const int mg = tid >> 7;
    const int nbase = blockIdx.x * 4;

    // ---- phase A: aggregate messages per node ----
    for (int ni = 0; ni < 4; ++ni) {
        int n = nbase + ni;
        int beg = offs[n], end = offs[n + 1];
        float acc[8];
#pragma unroll
        for (int i = 0; i < 8; ++i) acc[i] = 0.f;

        for (int cb = beg; cb < end; cb += 64) {
            int cnt = min(64, end - cb);
            __syncthreads();
            if (tid < cnt) {
                int ee = csr[cb + tid];
                s_e[tid] = ee;
                s_a[tid] = elem[ei[ee]];   // sender element
            }
            __syncthreads();
            for (int k = 0; k < cnt; ++k) {
                int e = s_e[k];
                float h = h_elem[s_a[k] * 128 + c];
                const unsigned short* rw = Rw + ((size_t)e << 9);
                const float4* Y4p = reinterpret_cast<const float4*>(Yw + ((size_t)e << 4));
                float4 ya = Y4p[mg * 2];
                float4 yb = Y4p[mg * 2 + 1];
                if (mg == 0) {
                    float r0 = bf2f(rw[c]) * h;
                    float r1 = bf2f(rw[128 + c]) * h;
                    float r2 = bf2f(rw[256 + c]) * h;
                    acc[0] = fmaf(r0, ya.x, acc[0]);
                    acc[1] = fmaf(r1, ya.y, acc[1]);
                    acc[2] = fmaf(r1, ya.z, acc[2]);
                    acc[3] = fmaf(r1, ya.w, acc[3]);
                    acc[4] = fmaf(r2, yb.x, acc[4]);
                    acc[5] = fmaf(r2, yb.y, acc[5]);
                    acc[6] = fmaf(r2, yb.z, acc[6]);
                    acc[7] = fmaf(r2, yb.w, acc[7]);
                } else {
                    float r2 = bf2f(rw[256 + c]) * h;
                    float r3 = bf2f(rw[384 + c]) * h;
                    acc[0] = fmaf(r2, ya.x, acc[0]);   // m=8 (l=2)
                    acc[1] = fmaf(r3, ya.y, acc[1]);
                    acc[2] = fmaf(r3, ya.z, acc[2]);
                    acc[3] = fmaf(r3, ya.w, acc[3]);
                    acc[4] = fmaf(r3, yb.x, acc[4]);
                    acc[5] = fmaf(r3, yb.y, acc[5]);
                    acc[6] = fmaf(r3, yb.z, acc[6]);
                    acc[7] = fmaf(r3, yb.w, acc[7]);
                }
            }
        }
#pragma unroll
        for (int i = 0; i < 8; ++i)
            aggT[c][ni * 16 + mg * 8 + i] = acc[i] * 0.0625f;   // /AVG
    }
    __syncthreads();

    // ---- phase B: A[n,m,d] = sum_c agg[n,m,c] * W_out[l(m),c,d] ----
    const int d = c;
    float accB[4][8];
#pragma unroll
    for (int ni = 0; ni < 4; ++ni)
#pragma unroll
        for (int i = 0; i < 8; ++i) accB[ni][i] = 0.f;

#pragma unroll 2
    for (int cc = 0; cc < 128; ++cc) {
        if (mg == 0) {
            float w0 = W_out[(0 * 128 + cc) * 128 + d];
            float w1 = W_out[(1 * 128 + cc) * 128 + d];
            float w2 = W_out[(2 * 128 + cc) * 128 + d];
#pragma unroll
            for (int ni = 0; ni < 4; ++ni) {
                const float* ag = &aggT[cc][ni * 16];
                accB[ni][0] = fmaf(w0, ag[0], accB[ni][0]);
                accB[ni][1] = fmaf(w1, ag[1], accB[ni][1]);
                accB[ni][2] = fmaf(w1, ag[2], accB[ni][2]);
                accB[ni][3] = fmaf(w1, ag[3], accB[ni][3]);
                accB[ni][4] = fmaf(w2, ag[4], accB[ni][4]);
                accB[ni][5] = fmaf(w2, ag[5], accB[ni][5]);
                accB[ni][6] = fmaf(w2, ag[6], accB[ni][6]);
                accB[ni][7] = fmaf(w2, ag[7], accB[ni][7]);
            }
        } else {
            float w2 = W_out[(2 * 128 + cc) * 128 + d];
            float w3 = W_out[(3 * 128 + cc) * 128 + d];
#pragma unroll
            for (int ni = 0; ni < 4; ++ni) {
                const float* ag = &aggT[cc][ni * 16 + 8];
                accB[ni][0] = fmaf(w2, ag[0], accB[ni][0]);
                accB[ni][1] = fmaf(w3, ag[1], accB[ni][1]);
                accB[ni][2] = fmaf(w3, ag[2], accB[ni][2]);
                accB[ni][3] = fmaf(w3, ag[3], accB[ni][3]);
                accB[ni][4] = fmaf(w3, ag[4], accB[ni][4]);
                accB[ni][5] = fmaf(w3, ag[5], accB[ni][5]);
                accB[ni][6] = fmaf(w3, ag[6], accB[ni][6]);
                accB[ni][7] = fmaf(w3, ag[7], accB[ni][7]);
            }
        }
    }
#pragma unroll
    for (int ni = 0; ni < 4; ++ni)
#pragma unroll
        for (int i = 0; i < 8; ++i)
            A_lds[ni][mg * 8 + i][d] = accB[ni][i];
    __syncthreads();

    // ---- phase C: norms, B0, p0, p1 ----
#pragma unroll 1
    for (int qq = 0; qq < 2; ++qq) {
        int ni = mg * 2 + qq;
        int n = nbase + ni;
        int a = elem[n];
        float Am[16];
#pragma unroll
        for (int m = 0; m < 16; ++m) Am[m] = A_lds[ni][m][d];
        float s = Am[0];
        float n1 = Am[1] * Am[1] + Am[2] * Am[2] + Am[3] * Am[3];
        float n2 = Am[4] * Am[4] + Am[5] * Am[5] + Am[6] * Am[6] + Am[7] * Am[7] + Am[8] * Am[8];
        float n3 = Am[9] * Am[9] + Am[10] * Am[10] + Am[11] * Am[11] + Am[12] * Am[12] +
                   Am[13] * Am[13] + Am[14] * Am[14] + Am[15] * Am[15];
        float s2 = s * s;
        float B0v[9] = {s, s2, s2 * s, n1, n2, n3, s * n1, s * n2, s * n3};
        const float* wp0 = Wp0 + (size_t)(a * 9) * 128 + d;
        float p0 = 0.f;
#pragma unroll
        for (int b = 0; b < 9; ++b) p0 = fmaf(wp0[b * 128], B0v[b], p0);
        float coefv[6] = {1.0f, s, s2, n1, n2, n3};
        const float* wp1 = Wp1 + (size_t)(a * 6) * 128 + d;
        float q1 = 0.f;
#pragma unroll
        for (int b = 0; b < 6; ++b) q1 = fmaf(wp1[b * 128], coefv[b], q1);
        p_lds[ni][0][d] = p0;
        p_lds[ni][1][d] = Am[1] * q1;
        p_lds[ni][2][d] = Am[2] * q1;
        p_lds[ni][3][d] = Am[3] * q1;
    }
    __syncthreads();

    // ---- phase D: o0 = p0 @ Wlin0 + sc0 ; o1 = p1 @ Wlin1 ----
    float oacc[8];
#pragma unroll
    for (int i = 0; i < 8; ++i) oacc[i] = 0.f;
#pragma unroll 2
    for (int cc = 0; cc < 128; ++cc) {
        float wa, wb;
        if (mg == 0) {
            wa = Wlin0[cc * 128 + d];
            wb = Wlin1[cc * 128 + d];
        } else {
            wb = Wlin1[cc * 128 + d];
            wa = wb;
        }
#pragma unroll
        for (int ni = 0; ni < 4; ++ni) {
            if (mg == 0) {
                oacc[ni * 2]     = fmaf(wa, p_lds[ni][0][cc], oacc[ni * 2]);
                oacc[ni * 2 + 1] = fmaf(wb, p_lds[ni][1][cc], oacc[ni * 2 + 1]);
            } else {
                oacc[ni * 2]     = fmaf(wa, p_lds[ni][2][cc], oacc[ni * 2]);
                oacc[ni * 2 + 1] = fmaf(wb, p_lds[ni][3][cc], oacc[ni * 2 + 1]);
            }
        }
    }
#pragma unroll
    for (int ni = 0; ni < 4; ++ni) {
        int n = nbase + ni;
        float v0 = oacc[ni * 2];
        float v1 = oacc[ni * 2 + 1];
        if (mg == 0) v0 += sc0e[elem[n] * 128 + d];
        int r0 = mg * 2;
        out[(size_t)n * 512 + (size_t)r0 * 128 + d] = v0;
        out[(size_t)n * 512 + (size_t)(r0 + 1) * 128 + d] = v1;
    }
}

// ---------------- launcher ----------------

extern "C" void kernel_launch(void* const* d_in, const int* in_sizes, int n_in,
                              void* d_out, int out_size, void* d_ws, size_t ws_size,
                              hipStream_t stream) {
    const float* x       = (const float*)d_in[0];
    const float* evec    = (const float*)d_in[1];
    const float* elen    = (const float*)d_in[2];
    const int*   eidx    = (const int*)d_in[3];
    const float* W_embed = (const float*)d_in[4];
    const float* W_skip  = (const float*)d_in[5];
    const float* W_up    = (const float*)d_in[6];
    const float* Wr1     = (const float*)d_in[7];
    const float* Wr2     = (const float*)d_in[8];
    const float* Wr3     = (const float*)d_in[9];
    const float* Wr4     = (const float*)d_in[10];
    const float* W_out   = (const float*)d_in[11];
    const float* Wp0     = (const float*)d_in[12];
    const float* Wp1     = (const float*)d_in[13];
    const float* Wlin0   = (const float*)d_in[14];
    const float* Wlin1   = (const float*)d_in[15];
    float* out = (float*)d_out;

    const int N = in_sizes[0] / NELEM;   // 8192
    const int E = in_sizes[2];           // 131072

    char* base = (char*)d_ws;
    size_t off = 0;
    auto alloc = [&](size_t b) { size_t o = off; off += (b + 255) & ~(size_t)255; return o; };
    int*   elem  = (int*)(base + alloc((size_t)N * 4));
    float* helem = (float*)(base + alloc((size_t)NELEM * C * 4));
    float* sc0e  = (float*)(base + alloc((size_t)NELEM * C * 4));
    float* W2T   = (float*)(base + alloc(4096 * 4));
    float* W3T   = (float*)(base + alloc(4096 * 4));
    float* W4T   = (float*)(base + alloc(32768 * 4));
    int*   deg   = (int*)(base + alloc((size_t)N * 4));
    int*   offs  = (int*)(base + alloc((size_t)(N + 1) * 4));
    int*   cur   = (int*)(base + alloc((size_t)N * 4));
    int*   csr   = (int*)(base + alloc((size_t)E * 4));
    float* Yw    = (float*)(base + alloc((size_t)E * 16 * 4));
    unsigned short* Rw = (unsigned short*)(base + alloc((size_t)E * 512 * 2));
    (void)ws_size; (void)n_in; (void)out_size;

    hipMemsetAsync(deg, 0, (size_t)N * 4, stream);
    hipMemsetAsync(cur, 0, (size_t)N * 4, stream);

    k_tables<<<1, 256, 0, stream>>>(W_embed, W_up, W_skip, helem, sc0e);
    k_elem<<<(N + 255) / 256, 256, 0, stream>>>(x, elem, N);
    k_transpose<<<160, 256, 0, stream>>>(Wr2, Wr3, Wr4, W2T, W3T, W4T);
    k_edge<<<(E + 255) / 256, 256, 0, stream>>>(evec, elen, Wr1, W2T, W3T, W4T, Yw, Rw, E);
    k_hist<<<(E + 255) / 256, 256, 0, stream>>>(eidx, deg, E);
    k_scan<<<1, 1024, 0, stream>>>(deg, offs, N);
    k_scatter<<<(E + 255) / 256, 256, 0, stream>>>(eidx, offs, cur, csr, E);
    k_node<<<N / 4, 256, 0, stream>>>(eidx, offs, csr, elem, Yw, Rw, helem, sc0e,
                                      W_out, Wp0, Wp1, Wlin0, Wlin1, out, E);
}

// Round 2
// 862.911 us; speedup vs baseline: 1.3333x; 1.3333x over previous
//
#include <hip/hip_runtime.h>

#define NELEM 10
#define C 128

__device__ inline unsigned short f2bf(float f) {
    unsigned x = __float_as_uint(f);
    unsigned r = (x + 0x7fffu + ((x >> 16) & 1u)) >> 16;
    return (unsigned short)r;
}
__device__ inline float bf2f(unsigned short b) {
    return __uint_as_float(((unsigned)b) << 16);
}

// ---------------- small prep kernels ----------------

__global__ void k_tables(const float* __restrict__ W_embed, const float* __restrict__ W_up,
                         const float* __restrict__ W_skip,
                         float* __restrict__ h_elem, float* __restrict__ sc0e) {
    int t = threadIdx.x;
    for (int idx = t; idx < NELEM * C; idx += 256) {
        int a = idx >> 7, c = idx & 127;
        float acc = 0.f, acc2 = 0.f;
        for (int k = 0; k < C; ++k) {
            float we = W_embed[a * C + k];
            acc  = fmaf(we, W_up[k * C + c], acc);
            acc2 = fmaf(we, W_skip[(k * NELEM + a) * C + c], acc2);
        }
        h_elem[idx] = acc;
        sc0e[idx] = acc2;
    }
}

__global__ void k_elem(const float* __restrict__ x, int* __restrict__ elem, int n) {
    int i = blockIdx.x * 256 + threadIdx.x;
    if (i >= n) return;
    int a = 0;
    float best = x[i * NELEM];
    for (int j = 1; j < NELEM; ++j) {
        float v = x[i * NELEM + j];
        if (v > best) { best = v; a = j; }
    }
    elem[i] = a;
}

__global__ void k_transpose(const float* __restrict__ Wr2, const float* __restrict__ Wr3,
                            const float* __restrict__ Wr4,
                            float* __restrict__ W2T, float* __restrict__ W3T,
                            float* __restrict__ W4T) {
    int i = blockIdx.x * 256 + threadIdx.x;
    if (i < 4096) { int j = i >> 6, k = i & 63; W2T[i] = Wr2[k * 64 + j]; }
    int i2 = i - 4096;
    if (i2 >= 0 && i2 < 4096) { int j = i2 >> 6, k = i2 & 63; W3T[i2] = Wr3[k * 64 + j]; }
    int i3 = i - 8192;
    if (i3 >= 0 && i3 < 32768) { int j = i3 >> 6, k = i3 & 63; W4T[i3] = Wr4[k * 512 + j]; }
}

// ---------------- CSR build ----------------

__global__ void k_hist(const int* __restrict__ ei, int* __restrict__ deg, int E) {
    int e = blockIdx.x * 256 + threadIdx.x;
    if (e < E) atomicAdd(&deg[ei[E + e]], 1);
}

__global__ void k_scan(const int* __restrict__ deg, int* __restrict__ offs, int n) {
    __shared__ int sums[1024];
    int tid = threadIdx.x;
    int base = tid * 8;
    int loc[8];
    int s = 0;
#pragma unroll
    for (int i = 0; i < 8; ++i) {
        loc[i] = s;
        if (base + i < n) s += deg[base + i];
    }
    sums[tid] = s;
    __syncthreads();
    for (int st = 1; st < 1024; st <<= 1) {
        int v = 0;
        if (tid >= st) v = sums[tid - st];
        __syncthreads();
        sums[tid] += v;
        __syncthreads();
    }
    int excl = sums[tid] - s;
#pragma unroll
    for (int i = 0; i < 8; ++i)
        if (base + i < n) offs[base + i] = excl + loc[i];
    if (tid == 1023) offs[n] = sums[1023];
}

__global__ void k_scatter(const int* __restrict__ ei, const int* __restrict__ offs,
                          int* __restrict__ cur, int* __restrict__ csr, int E) {
    int e = blockIdx.x * 256 + threadIdx.x;
    if (e < E) {
        int r = ei[E + e];
        int p = atomicAdd(&cur[r], 1);
        csr[offs[r] + p] = e;
    }
}

// ---------------- edge kernel: Y + radial MLP (register-resident) ----------------

__global__ __launch_bounds__(256, 2) void k_edge(
    const float* __restrict__ evec, const float* __restrict__ elen,
    const float* __restrict__ Wr1,
    const float* __restrict__ W2T, const float* __restrict__ W3T,
    const float* __restrict__ W4T,
    float* __restrict__ Yw, unsigned short* __restrict__ Rw, int E)
{
    __shared__ float t_lds[256 * 65];
    const int tid = threadIdx.x;
    const int e = blockIdx.x * 256 + tid;
    if (e >= E) return;

    float vx = evec[3 * e], vy = evec[3 * e + 1], vz = evec[3 * e + 2];
    float inv = rsqrtf(vx * vx + vy * vy + vz * vz);
    float ux = vx * inv, uy = vy * inv, uz = vz * inv;

    const float s3    = 1.7320508075688772f;
    const float s5h   = 1.118033988749895f;
    const float s15   = 3.872983346207417f;
    const float s15h  = 1.9364916731037085f;
    const float s70_4 = 2.091650066335189f;
    const float s105  = 10.246950765959598f;
    const float s105_2= 5.123475382979799f;
    const float s42_4 = 1.6201851746019651f;
    const float s7_2  = 1.3228756555322954f;

    float xx = ux * ux, yy = uy * uy, zz = uz * uz;
    float4* yo = reinterpret_cast<float4*>(Yw + ((size_t)e << 4));
    yo[0] = make_float4(1.0f, s3 * ux, s3 * uy, s3 * uz);
    yo[1] = make_float4(s15 * ux * uy, s15 * uy * uz, s5h * (3.0f * zz - 1.0f), s15 * ux * uz);
    yo[2] = make_float4(s15h * (xx - yy),
                        s70_4 * uy * (3.0f * xx - yy),
                        s105 * ux * uy * uz,
                        s42_4 * uy * (5.0f * zz - 1.0f));
    yo[3] = make_float4(s7_2 * uz * (5.0f * zz - 3.0f),
                        s42_4 * ux * (5.0f * zz - 1.0f),
                        s105_2 * uz * (xx - yy),
                        s70_4 * ux * (xx - 3.0f * yy));

    float r = elen[e];
    float u = r * 0.2f;
    float u2 = u * u;
    float u5 = u2 * u2 * u;
    float env = 1.0f - 21.0f * u5 + 35.0f * u5 * u - 15.0f * u5 * u2;
    if (u >= 1.0f) env = 0.0f;
    float th = 3.14159265358979323846f * u;
    float s1 = __sinf(th), c1 = __cosf(th);
    float pref = 0.6324555320336759f * env / r;
    float ef[8];
    float sn = s1, cn = c1;
    ef[0] = pref * sn;
#pragma unroll
    for (int nn = 1; nn < 8; ++nn) {
        float sn1 = sn * c1 + cn * s1;
        float cn1 = cn * c1 - sn * s1;
        sn = sn1; cn = cn1;
        ef[nn] = pref * sn;
    }

    // layer 1: 8 -> 64 + silu
    float t[64];
#pragma unroll
    for (int j = 0; j < 64; ++j) t[j] = 0.0f;
#pragma unroll
    for (int i = 0; i < 8; ++i) {
        const float4* w1r = reinterpret_cast<const float4*>(Wr1 + i * 64);
        float efi = ef[i];
#pragma unroll
        for (int j4 = 0; j4 < 16; ++j4) {
            float4 w = w1r[j4];
            t[4 * j4 + 0] = fmaf(efi, w.x, t[4 * j4 + 0]);
            t[4 * j4 + 1] = fmaf(efi, w.y, t[4 * j4 + 1]);
            t[4 * j4 + 2] = fmaf(efi, w.z, t[4 * j4 + 2]);
            t[4 * j4 + 3] = fmaf(efi, w.w, t[4 * j4 + 3]);
        }
    }
#pragma unroll
    for (int j = 0; j < 64; ++j) {
        float v = t[j];
        t[j] = v * __builtin_amdgcn_rcpf(1.0f + __expf(-v));
    }

    float* myt = t_lds + tid * 65;

    // layer 2: 64 -> 64 + silu (2 outputs/iter)
#pragma unroll 1
    for (int j2 = 0; j2 < 32; ++j2) {
        const float4* wr0 = reinterpret_cast<const float4*>(W2T + (size_t)(2 * j2) * 64);
        const float4* wr1 = wr0 + 16;
        float a0 = 0.f, a1 = 0.f, a2 = 0.f, a3 = 0.f;
        float b0 = 0.f, b1 = 0.f, b2 = 0.f, b3 = 0.f;
#pragma unroll
        for (int i4 = 0; i4 < 16; ++i4) {
            float4 wA = wr0[i4], wB = wr1[i4];
            a0 = fmaf(t[4 * i4 + 0], wA.x, a0); b0 = fmaf(t[4 * i4 + 0], wB.x, b0);
            a1 = fmaf(t[4 * i4 + 1], wA.y, a1); b1 = fmaf(t[4 * i4 + 1], wB.y, b1);
            a2 = fmaf(t[4 * i4 + 2], wA.z, a2); b2 = fmaf(t[4 * i4 + 2], wB.z, b2);
            a3 = fmaf(t[4 * i4 + 3], wA.w, a3); b3 = fmaf(t[4 * i4 + 3], wB.w, b3);
        }
        float sA = (a0 + a1) + (a2 + a3);
        float sB = (b0 + b1) + (b2 + b3);
        myt[2 * j2]     = sA * __builtin_amdgcn_rcpf(1.0f + __expf(-sA));
        myt[2 * j2 + 1] = sB * __builtin_amdgcn_rcpf(1.0f + __expf(-sB));
    }
#pragma unroll
    for (int j = 0; j < 64; ++j) t[j] = myt[j];

    // layer 3: 64 -> 64 + silu
#pragma unroll 1
    for (int j2 = 0; j2 < 32; ++j2) {
        const float4* wr0 = reinterpret_cast<const float4*>(W3T + (size_t)(2 * j2) * 64);
        const float4* wr1 = wr0 + 16;
        float a0 = 0.f, a1 = 0.f, a2 = 0.f, a3 = 0.f;
        float b0 = 0.f, b1 = 0.f, b2 = 0.f, b3 = 0.f;
#pragma unroll
        for (int i4 = 0; i4 < 16; ++i4) {
            float4 wA = wr0[i4], wB = wr1[i4];
            a0 = fmaf(t[4 * i4 + 0], wA.x, a0); b0 = fmaf(t[4 * i4 + 0], wB.x, b0);
            a1 = fmaf(t[4 * i4 + 1], wA.y, a1); b1 = fmaf(t[4 * i4 + 1], wB.y, b1);
            a2 = fmaf(t[4 * i4 + 2], wA.z, a2); b2 = fmaf(t[4 * i4 + 2], wB.z, b2);
            a3 = fmaf(t[4 * i4 + 3], wA.w, a3); b3 = fmaf(t[4 * i4 + 3], wB.w, b3);
        }
        float sA = (a0 + a1) + (a2 + a3);
        float sB = (b0 + b1) + (b2 + b3);
        myt[2 * j2]     = sA * __builtin_amdgcn_rcpf(1.0f + __expf(-sA));
        myt[2 * j2 + 1] = sB * __builtin_amdgcn_rcpf(1.0f + __expf(-sB));
    }
#pragma unroll
    for (int j = 0; j < 64; ++j) t[j] = myt[j];

    // layer 4: 64 -> 512, store bf16 pairs
    unsigned* op = reinterpret_cast<unsigned*>(Rw + ((size_t)e << 9));
#pragma unroll 1
    for (int j2 = 0; j2 < 256; ++j2) {
        const float4* wr0 = reinterpret_cast<const float4*>(W4T + ((size_t)(2 * j2) << 6));
        const float4* wr1 = wr0 + 16;
        float a0 = 0.f, a1 = 0.f, a2 = 0.f, a3 = 0.f;
        float b0 = 0.f, b1 = 0.f, b2 = 0.f, b3 = 0.f;
#pragma unroll
        for (int i4 = 0; i4 < 16; ++i4) {
            float4 wA = wr0[i4], wB = wr1[i4];
            a0 = fmaf(t[4 * i4 + 0], wA.x, a0); b0 = fmaf(t[4 * i4 + 0], wB.x, b0);
            a1 = fmaf(t[4 * i4 + 1], wA.y, a1); b1 = fmaf(t[4 * i4 + 1], wB.y, b1);
            a2 = fmaf(t[4 * i4 + 2], wA.z, a2); b2 = fmaf(t[4 * i4 + 2], wB.z, b2);
            a3 = fmaf(t[4 * i4 + 3], wA.w, a3); b3 = fmaf(t[4 * i4 + 3], wB.w, b3);
        }
        float sA = (a0 + a1) + (a2 + a3);
        float sB = (b0 + b1) + (b2 + b3);
        op[j2] = (unsigned)f2bf(sA) | ((unsigned)f2bf(sB) << 16);
    }
}

// ---------------- aggregation kernel: one node per block ----------------

__global__ __launch_bounds__(256) void k_agg(
    const int* __restrict__ ei, const int* __restrict__ offs, const int* __restrict__ csr,
    const int* __restrict__ elem,
    const float* __restrict__ Yw, const unsigned short* __restrict__ Rw,
    const float* __restrict__ h_elem, float* __restrict__ agg, int E)
{
    __shared__ int s_e[64];
    __shared__ int s_a[64];
    const int tid = threadIdx.x;
    const int c = tid & 127;
    const int mg = tid >> 7;
    const int n = blockIdx.x;
    int beg = offs[n], end = offs[n + 1];

    float acc[8];
#pragma unroll
    for (int i = 0; i < 8; ++i) acc[i] = 0.f;

    for (int cb = beg; cb < end; cb += 64) {
        int cnt = min(64, end - cb);
        __syncthreads();
        if (tid < cnt) {
            int ee = csr[cb + tid];
            s_e[tid] = ee;
            s_a[tid] = elem[ei[ee]];
        }
        __syncthreads();
#pragma unroll 2
        for (int k = 0; k < cnt; ++k) {
            int e = s_e[k];
            float h = h_elem[s_a[k] * 128 + c];
            const unsigned short* rw = Rw + ((size_t)e << 9);
            const float4* Y4p = reinterpret_cast<const float4*>(Yw + ((size_t)e << 4));
            float4 ya = Y4p[mg * 2];
            float4 yb = Y4p[mg * 2 + 1];
            if (mg == 0) {
                float r0 = bf2f(rw[c]) * h;
                float r1 = bf2f(rw[128 + c]) * h;
                float r2 = bf2f(rw[256 + c]) * h;
                acc[0] = fmaf(r0, ya.x, acc[0]);
                acc[1] = fmaf(r1, ya.y, acc[1]);
                acc[2] = fmaf(r1, ya.z, acc[2]);
                acc[3] = fmaf(r1, ya.w, acc[3]);
                acc[4] = fmaf(r2, yb.x, acc[4]);
                acc[5] = fmaf(r2, yb.y, acc[5]);
                acc[6] = fmaf(r2, yb.z, acc[6]);
                acc[7] = fmaf(r2, yb.w, acc[7]);
            } else {
                float r2 = bf2f(rw[256 + c]) * h;
                float r3 = bf2f(rw[384 + c]) * h;
                acc[0] = fmaf(r2, ya.x, acc[0]);
                acc[1] = fmaf(r3, ya.y, acc[1]);
                acc[2] = fmaf(r3, ya.z, acc[2]);
                acc[3] = fmaf(r3, ya.w, acc[3]);
                acc[4] = fmaf(r3, yb.x, acc[4]);
                acc[5] = fmaf(r3, yb.y, acc[5]);
                acc[6] = fmaf(r3, yb.z, acc[6]);
                acc[7] = fmaf(r3, yb.w, acc[7]);
            }
        }
    }
#pragma unroll
    for (int i = 0; i < 8; ++i)
        agg[((size_t)n * 16 + mg * 8 + i) * 128 + c] = acc[i] * 0.0625f;
}

// ---------------- node tail kernel: 2 nodes per block ----------------

__global__ __launch_bounds__(256) void k_node2(
    const int* __restrict__ elem, const float* __restrict__ agg,
    const float* __restrict__ sc0e, const float* __restrict__ W_out,
    const float* __restrict__ Wp0, const float* __restrict__ Wp1,
    const float* __restrict__ Wlin0, const float* __restrict__ Wlin1,
    float* __restrict__ out)
{
    __shared__ float buf[2][16][128];   // agg (phase B input), then A (phase C input)
    __shared__ float p_lds[2][4][128];
    const int tid = threadIdx.x;
    const int d = tid & 127;
    const int mg = tid >> 7;
    const int nbase = blockIdx.x * 2;

    float* bflat = &buf[0][0][0];
    const float* ag = agg + (size_t)nbase * 2048;
    for (int i = tid; i < 4096; i += 256) bflat[i] = ag[i];
    __syncthreads();

    // phase B: A[n,m,d] = sum_cc agg[n,m,cc] * W_out[l(m),cc,d]
    float accB[2][8];
#pragma unroll
    for (int ni = 0; ni < 2; ++ni)
#pragma unroll
        for (int i = 0; i < 8; ++i) accB[ni][i] = 0.f;

#pragma unroll 2
    for (int cc = 0; cc < 128; ++cc) {
        if (mg == 0) {
            float w0 = W_out[(0 * 128 + cc) * 128 + d];
            float w1 = W_out[(1 * 128 + cc) * 128 + d];
            float w2 = W_out[(2 * 128 + cc) * 128 + d];
#pragma unroll
            for (int ni = 0; ni < 2; ++ni) {
                const float* a = &buf[ni][0][cc];
                accB[ni][0] = fmaf(w0, a[0 * 128], accB[ni][0]);
                accB[ni][1] = fmaf(w1, a[1 * 128], accB[ni][1]);
                accB[ni][2] = fmaf(w1, a[2 * 128], accB[ni][2]);
                accB[ni][3] = fmaf(w1, a[3 * 128], accB[ni][3]);
                accB[ni][4] = fmaf(w2, a[4 * 128], accB[ni][4]);
                accB[ni][5] = fmaf(w2, a[5 * 128], accB[ni][5]);
                accB[ni][6] = fmaf(w2, a[6 * 128], accB[ni][6]);
                accB[ni][7] = fmaf(w2, a[7 * 128], accB[ni][7]);
            }
        } else {
            float w2 = W_out[(2 * 128 + cc) * 128 + d];
            float w3 = W_out[(3 * 128 + cc) * 128 + d];
#pragma unroll
            for (int ni = 0; ni < 2; ++ni) {
                const float* a = &buf[ni][8][cc];
                accB[ni][0] = fmaf(w2, a[0 * 128], accB[ni][0]);
                accB[ni][1] = fmaf(w3, a[1 * 128], accB[ni][1]);
                accB[ni][2] = fmaf(w3, a[2 * 128], accB[ni][2]);
                accB[ni][3] = fmaf(w3, a[3 * 128], accB[ni][3]);
                accB[ni][4] = fmaf(w3, a[4 * 128], accB[ni][4]);
                accB[ni][5] = fmaf(w3, a[5 * 128], accB[ni][5]);
                accB[ni][6] = fmaf(w3, a[6 * 128], accB[ni][6]);
                accB[ni][7] = fmaf(w3, a[7 * 128], accB[ni][7]);
            }
        }
    }
    __syncthreads();   // done reading agg from buf
#pragma unroll
    for (int ni = 0; ni < 2; ++ni)
#pragma unroll
        for (int i = 0; i < 8; ++i)
            buf[ni][mg * 8 + i][d] = accB[ni][i];
    __syncthreads();

    // phase C: norms, B0, p0, p1 (each mg half owns one node)
    {
        int n = nbase + mg;
        int a = elem[n];
        float Am[16];
#pragma unroll
        for (int m = 0; m < 16; ++m) Am[m] = buf[mg][m][d];
        float s = Am[0];
        float n1 = Am[1] * Am[1] + Am[2] * Am[2] + Am[3] * Am[3];
        float n2 = Am[4] * Am[4] + Am[5] * Am[5] + Am[6] * Am[6] + Am[7] * Am[7] + Am[8] * Am[8];
        float n3 = Am[9] * Am[9] + Am[10] * Am[10] + Am[11] * Am[11] + Am[12] * Am[12] +
                   Am[13] * Am[13] + Am[14] * Am[14] + Am[15] * Am[15];
        float s2 = s * s;
        float B0v[9] = {s, s2, s2 * s, n1, n2, n3, s * n1, s * n2, s * n3};
        const float* wp0 = Wp0 + (size_t)(a * 9) * 128 + d;
        float p0 = 0.f;
#pragma unroll
        for (int b = 0; b < 9; ++b) p0 = fmaf(wp0[b * 128], B0v[b], p0);
        float coefv[6] = {1.0f, s, s2, n1, n2, n3};
        const float* wp1 = Wp1 + (size_t)(a * 6) * 128 + d;
        float q1 = 0.f;
#pragma unroll
        for (int b = 0; b < 6; ++b) q1 = fmaf(wp1[b * 128], coefv[b], q1);
        p_lds[mg][0][d] = p0;
        p_lds[mg][1][d] = Am[1] * q1;
        p_lds[mg][2][d] = Am[2] * q1;
        p_lds[mg][3][d] = Am[3] * q1;
    }
    __syncthreads();

    // phase D: o0 = p0 @ Wlin0 + sc0 ; o1 = p1 @ Wlin1
    float oacc[4] = {0.f, 0.f, 0.f, 0.f};
#pragma unroll 2
    for (int cc = 0; cc < 128; ++cc) {
        float wb = Wlin1[cc * 128 + d];
        float wa = (mg == 0) ? Wlin0[cc * 128 + d] : wb;
#pragma unroll
        for (int ni = 0; ni < 2; ++ni) {
            oacc[ni * 2]     = fmaf(wa, p_lds[ni][mg * 2 + 0][cc], oacc[ni * 2]);
            oacc[ni * 2 + 1] = fmaf(wb, p_lds[ni][mg * 2 + 1][cc], oacc[ni * 2 + 1]);
        }
    }
#pragma unroll
    for (int ni = 0; ni < 2; ++ni) {
        int n = nbase + ni;
        float v0 = oacc[ni * 2];
        float v1 = oacc[ni * 2 + 1];
        if (mg == 0) v0 += sc0e[elem[n] * 128 + d];
        out[(size_t)n * 512 + (size_t)(mg * 2) * 128 + d] = v0;
        out[(size_t)n * 512 + (size_t)(mg * 2 + 1) * 128 + d] = v1;
    }
}

// ---------------- fallback fused node kernel (if ws too small for agg) ----------------

__global__ __launch_bounds__(256) void k_node(
    const int* __restrict__ ei, const int* __restrict__ offs, const int* __restrict__ csr,
    const int* __restrict__ elem,
    const float* __restrict__ Yw, const unsigned short* __restrict__ Rw,
    const float* __restrict__ h_elem, const float* __restrict__ sc0e,
    const float* __restrict__ W_out, const float* __restrict__ Wp0,
    const float* __restrict__ Wp1, const float* __restrict__ Wlin0,
    const float* __restrict__ Wlin1, float* __restrict__ out, int E)
{
    __shared__ float aggT[128][68];
    __shared__ float A_lds[4][16][128];
    __shared__ float p_lds[4][4][128];
    __shared__ int s_e[64];
    __shared__ int s_a[64];

    const int tid = threadIdx.x;
    const int c = tid & 127;
    const int mg = tid >> 7;
    const int nbase = blockIdx.x * 4;

    for (int ni = 0; ni < 4; ++ni) {
        int n = nbase + ni;
        int beg = offs[n], end = offs[n + 1];
        float acc[8];
#pragma unroll
        for (int i = 0; i < 8; ++i) acc[i] = 0.f;

        for (int cb = beg; cb < end; cb += 64) {
            int cnt = min(64, end - cb);
            __syncthreads();
            if (tid < cnt) {
                int ee = csr[cb + tid];
                s_e[tid] = ee;
                s_a[tid] = elem[ei[ee]];
            }
            __syncthreads();
            for (int k = 0; k < cnt; ++k) {
                int e = s_e[k];
                float h = h_elem[s_a[k] * 128 + c];
                const unsigned short* rw = Rw + ((size_t)e << 9);
                const float4* Y4p = reinterpret_cast<const float4*>(Yw + ((size_t)e << 4));
                float4 ya = Y4p[mg * 2];
                float4 yb = Y4p[mg * 2 + 1];
                if (mg == 0) {
                    float r0 = bf2f(rw[c]) * h;
                    float r1 = bf2f(rw[128 + c]) * h;
                    float r2 = bf2f(rw[256 + c]) * h;
                    acc[0] = fmaf(r0, ya.x, acc[0]);
                    acc[1] = fmaf(r1, ya.y, acc[1]);
                    acc[2] = fmaf(r1, ya.z, acc[2]);
                    acc[3] = fmaf(r1, ya.w, acc[3]);
                    acc[4] = fmaf(r2, yb.x, acc[4]);
                    acc[5] = fmaf(r2, yb.y, acc[5]);
                    acc[6] = fmaf(r2, yb.z, acc[6]);
                    acc[7] = fmaf(r2, yb.w, acc[7]);
                } else {
                    float r2 = bf2f(rw[256 + c]) * h;
                    float r3 = bf2f(rw[384 + c]) * h;
                    acc[0] = fmaf(r2, ya.x, acc[0]);
                    acc[1] = fmaf(r3, ya.y, acc[1]);
                    acc[2] = fmaf(r3, ya.z, acc[2]);
                    acc[3] = fmaf(r3, ya.w, acc[3]);
                    acc[4] = fmaf(r3, yb.x, acc[4]);
                    acc[5] = fmaf(r3, yb.y, acc[5]);
                    acc[6] = fmaf(r3, yb.z, acc[6]);
                    acc[7] = fmaf(r3, yb.w, acc[7]);
                }
            }
        }
#pragma unroll
        for (int i = 0; i < 8; ++i)
            aggT[c][ni * 16 + mg * 8 + i] = acc[i] * 0.0625f;
    }
    __syncthreads();

    const int d = c;
    float accB[4][8];
#pragma unroll
    for (int ni = 0; ni < 4; ++ni)
#pragma unroll
        for (int i = 0; i < 8; ++i) accB[ni][i] = 0.f;

#pragma unroll 2
    for (int cc = 0; cc < 128; ++cc) {
        if (mg == 0) {
            float w0 = W_out[(0 * 128 + cc) * 128 + d];
            float w1 = W_out[(1 * 128 + cc) * 128 + d];
            float w2 = W_out[(2 * 128 + cc) * 128 + d];
#pragma unroll
            for (int ni = 0; ni < 4; ++ni) {
                const float* ag = &aggT[cc][ni * 16];
                accB[ni][0] = fmaf(w0, ag[0], accB[ni][0]);
                accB[ni][1] = fmaf(w1, ag[1], accB[ni][1]);
                accB[ni][2] = fmaf(w1, ag[2], accB[ni][2]);
                accB[ni][3] = fmaf(w1, ag[3], accB[ni][3]);
                accB[ni][4] = fmaf(w2, ag[4], accB[ni][4]);
                accB[ni][5] = fmaf(w2, ag[5], accB[ni][5]);
                accB[ni][6] = fmaf(w2, ag[6], accB[ni][6]);
                accB[ni][7] = fmaf(w2, ag[7], accB[ni][7]);
            }
        } else {
            float w2 = W_out[(2 * 128 + cc) * 128 + d];
            float w3 = W_out[(3 * 128 + cc) * 128 + d];
#pragma unroll
            for (int ni = 0; ni < 4; ++ni) {
                const float* ag = &aggT[cc][ni * 16 + 8];
                accB[ni][0] = fmaf(w2, ag[0], accB[ni][0]);
                accB[ni][1] = fmaf(w3, ag[1], accB[ni][1]);
                accB[ni][2] = fmaf(w3, ag[2], accB[ni][2]);
                accB[ni][3] = fmaf(w3, ag[3], accB[ni][3]);
                accB[ni][4] = fmaf(w3, ag[4], accB[ni][4]);
                accB[ni][5] = fmaf(w3, ag[5], accB[ni][5]);
                accB[ni][6] = fmaf(w3, ag[6], accB[ni][6]);
                accB[ni][7] = fmaf(w3, ag[7], accB[ni][7]);
            }
        }
    }
#pragma unroll
    for (int ni = 0; ni < 4; ++ni)
#pragma unroll
        for (int i = 0; i < 8; ++i)
            A_lds[ni][mg * 8 + i][d] = accB[ni][i];
    __syncthreads();

#pragma unroll 1
    for (int qq = 0; qq < 2; ++qq) {
        int ni = mg * 2 + qq;
        int n = nbase + ni;
        int a = elem[n];
        float Am[16];
#pragma unroll
        for (int m = 0; m < 16; ++m) Am[m] = A_lds[ni][m][d];
        float s = Am[0];
        float n1 = Am[1] * Am[1] + Am[2] * Am[2] + Am[3] * Am[3];
        float n2 = Am[4] * Am[4] + Am[5] * Am[5] + Am[6] * Am[6] + Am[7] * Am[7] + Am[8] * Am[8];
        float n3 = Am[9] * Am[9] + Am[10] * Am[10] + Am[11] * Am[11] + Am[12] * Am[12] +
                   Am[13] * Am[13] + Am[14] * Am[14] + Am[15] * Am[15];
        float s2 = s * s;
        float B0v[9] = {s, s2, s2 * s, n1, n2, n3, s * n1, s * n2, s * n3};
        const float* wp0 = Wp0 + (size_t)(a * 9) * 128 + d;
        float p0 = 0.f;
#pragma unroll
        for (int b = 0; b < 9; ++b) p0 = fmaf(wp0[b * 128], B0v[b], p0);
        float coefv[6] = {1.0f, s, s2, n1, n2, n3};
        const float* wp1 = Wp1 + (size_t)(a * 6) * 128 + d;
        float q1 = 0.f;
#pragma unroll
        for (int b = 0; b < 6; ++b) q1 = fmaf(wp1[b * 128], coefv[b], q1);
        p_lds[ni][0][d] = p0;
        p_lds[ni][1][d] = Am[1] * q1;
        p_lds[ni][2][d] = Am[2] * q1;
        p_lds[ni][3][d] = Am[3] * q1;
    }
    __syncthreads();

    float oacc[8];
#pragma unroll
    for (int i = 0; i < 8; ++i) oacc[i] = 0.f;
#pragma unroll 2
    for (int cc = 0; cc < 128; ++cc) {
        float wb = Wlin1[cc * 128 + d];
        float wa = (mg == 0) ? Wlin0[cc * 128 + d] : wb;
#pragma unroll
        for (int ni = 0; ni < 4; ++ni) {
            oacc[ni * 2]     = fmaf(wa, p_lds[ni][mg * 2 + 0][cc], oacc[ni * 2]);
            oacc[ni * 2 + 1] = fmaf(wb, p_lds[ni][mg * 2 + 1][cc], oacc[ni * 2 + 1]);
        }
    }
#pragma unroll
    for (int ni = 0; ni < 4; ++ni) {
        int n = nbase + ni;
        float v0 = oacc[ni * 2];
        float v1 = oacc[ni * 2 + 1];
        if (mg == 0) v0 += sc0e[elem[n] * 128 + d];
        int r0 = mg * 2;
        out[(size_t)n * 512 + (size_t)r0 * 128 + d] = v0;
        out[(size_t)n * 512 + (size_t)(r0 + 1) * 128 + d] = v1;
    }
}

// ---------------- launcher ----------------

extern "C" void kernel_launch(void* const* d_in, const int* in_sizes, int n_in,
                              void* d_out, int out_size, void* d_ws, size_t ws_size,
                              hipStream_t stream) {
    const float* x       = (const float*)d_in[0];
    const float* evec    = (const float*)d_in[1];
    const float* elen    = (const float*)d_in[2];
    const int*   eidx    = (const int*)d_in[3];
    const float* W_embed = (const float*)d_in[4];
    const float* W_skip  = (const float*)d_in[5];
    const float* W_up    = (const float*)d_in[6];
    const float* Wr1     = (const float*)d_in[7];
    const float* Wr2     = (const float*)d_in[8];
    const float* Wr3     = (const float*)d_in[9];
    const float* Wr4     = (const float*)d_in[10];
    const float* W_out   = (const float*)d_in[11];
    const float* Wp0     = (const float*)d_in[12];
    const float* Wp1     = (const float*)d_in[13];
    const float* Wlin0   = (const float*)d_in[14];
    const float* Wlin1   = (const float*)d_in[15];
    float* out = (float*)d_out;

    const int N = in_sizes[0] / NELEM;
    const int E = in_sizes[2];

    char* base = (char*)d_ws;
    size_t off = 0;
    auto alloc = [&](size_t b) { size_t o = off; off += (b + 255) & ~(size_t)255; return o; };
    int*   elem  = (int*)(base + alloc((size_t)N * 4));
    float* helem = (float*)(base + alloc((size_t)NELEM * C * 4));
    float* sc0e  = (float*)(base + alloc((size_t)NELEM * C * 4));
    float* W2T   = (float*)(base + alloc(4096 * 4));
    float* W3T   = (float*)(base + alloc(4096 * 4));
    float* W4T   = (float*)(base + alloc(32768 * 4));
    int*   deg   = (int*)(base + alloc((size_t)N * 4));
    int*   offs  = (int*)(base + alloc((size_t)(N + 1) * 4));
    int*   cur   = (int*)(base + alloc((size_t)N * 4));
    int*   csr   = (int*)(base + alloc((size_t)E * 4));
    float* Yw    = (float*)(base + alloc((size_t)E * 16 * 4));
    unsigned short* Rw = (unsigned short*)(base + alloc((size_t)E * 512 * 2));
    float* agg   = (float*)(base + alloc((size_t)N * 16 * 128 * 4));
    size_t need = off;
    (void)n_in; (void)out_size;

    hipMemsetAsync(deg, 0, (size_t)N * 4, stream);
    hipMemsetAsync(cur, 0, (size_t)N * 4, stream);

    k_tables<<<1, 256, 0, stream>>>(W_embed, W_up, W_skip, helem, sc0e);
    k_elem<<<(N + 255) / 256, 256, 0, stream>>>(x, elem, N);
    k_transpose<<<160, 256, 0, stream>>>(Wr2, Wr3, Wr4, W2T, W3T, W4T);
    k_edge<<<(E + 255) / 256, 256, 0, stream>>>(evec, elen, Wr1, W2T, W3T, W4T, Yw, Rw, E);
    k_hist<<<(E + 255) / 256, 256, 0, stream>>>(eidx, deg, E);
    k_scan<<<1, 1024, 0, stream>>>(deg, offs, N);
    k_scatter<<<(E + 255) / 256, 256, 0, stream>>>(eidx, offs, cur, csr, E);

    if (ws_size >= need) {
        k_agg<<<N, 256, 0, stream>>>(eidx, offs, csr, elem, Yw, Rw, helem, agg, E);
        k_node2<<<N / 2, 256, 0, stream>>>(elem, agg, sc0e, W_out, Wp0, Wp1,
                                           Wlin0, Wlin1, out);
    } else {
        k_node<<<N / 4, 256, 0, stream>>>(eidx, offs, csr, elem, Yw, Rw, helem, sc0e,
                                          W_out, Wp0, Wp1, Wlin0, Wlin1, out, E);
    }
}